// Round 1
// baseline (465.816 us; speedup 1.0000x reference)
//
#include <hip/hip_runtime.h>
#include <math.h>

#define N_NODES 8192
#define F_IN    512
#define H1      32
#define H2      16

#define FMA4(acc, s, v) do { (acc).x += (s)*(v).x; (acc).y += (s)*(v).y; \
                             (acc).z += (s)*(v).z; (acc).w += (s)*(v).w; } while(0)

// ---------------- Kernel 1: XW0 = features @ W0  [8192,512]x[512,32] ----------------
__global__ __launch_bounds__(256) void k_xw0(const float* __restrict__ feat,
                                             const float* __restrict__ W0,
                                             float* __restrict__ xw0) {
    __shared__ float w0s[F_IN * H1];            // 64 KiB
    float4* w0s_v = (float4*)w0s;
    const float4* W0_v = (const float4*)W0;
    int t = threadIdx.x;
    #pragma unroll
    for (int i = 0; i < 16; ++i) w0s_v[t + i * 256] = W0_v[t + i * 256];
    __syncthreads();

    int row = blockIdx.x * 32 + (t >> 3);       // 32 rows / block
    int cg  = (t & 7) * 4;                      // 4 cols / thread
    const float4* frow_v = (const float4*)(feat + (size_t)row * F_IN);

    float4 acc = {0.f, 0.f, 0.f, 0.f};
    #pragma unroll 4
    for (int k0 = 0; k0 < F_IN; k0 += 4) {
        float4 f  = frow_v[k0 >> 2];
        float4 w0 = *(float4*)&w0s[(k0 + 0) * H1 + cg];
        float4 w1 = *(float4*)&w0s[(k0 + 1) * H1 + cg];
        float4 w2 = *(float4*)&w0s[(k0 + 2) * H1 + cg];
        float4 w3 = *(float4*)&w0s[(k0 + 3) * H1 + cg];
        FMA4(acc, f.x, w0);
        FMA4(acc, f.y, w1);
        FMA4(acc, f.z, w2);
        FMA4(acc, f.w, w3);
    }
    *(float4*)&xw0[row * H1 + cg] = acc;
}

// ---------------- Kernel 2: h1acc += A @ XW0 (atomic scatter, d=32) ----------------
__global__ __launch_bounds__(256) void k_spmm1(const int* __restrict__ rows,
                                               const int* __restrict__ cols,
                                               const float* __restrict__ vals,
                                               const float* __restrict__ xw0,
                                               float* __restrict__ h1acc, int E) {
    int t = blockIdx.x * 256 + threadIdx.x;
    int e = t >> 3;                  // 8 threads / edge
    if (e >= E) return;
    int part = (t & 7) * 4;
    int r = rows[e], c = cols[e];
    float v = vals[e];
    float4 x = *(const float4*)&xw0[c * H1 + part];
    float* dst = &h1acc[r * H1 + part];
    atomicAdd(dst + 0, v * x.x);
    atomicAdd(dst + 1, v * x.y);
    atomicAdd(dst + 2, v * x.z);
    atomicAdd(dst + 3, v * x.w);
}

// ---------------- Kernel 3: Y[h] = relu(h1acc) @ W(h), h = 0,1,2 ----------------
__global__ __launch_bounds__(256) void k_heads(const float* __restrict__ h1acc,
                                               const float* __restrict__ W1,
                                               const float* __restrict__ W2,
                                               const float* __restrict__ W3,
                                               float* __restrict__ Y) {
    __shared__ float ws[3 * H1 * H2];           // 6 KiB
    int t = threadIdx.x;
    for (int i = t; i < H1 * H2; i += 256) {
        ws[i]            = W1[i];
        ws[512 + i]      = W2[i];
        ws[1024 + i]     = W3[i];
    }
    __syncthreads();

    int g   = blockIdx.x * 256 + t;             // g < N*H2
    int row = g >> 4, col = g & 15;
    const float* h = &h1acc[row * H1];
    float a0 = 0.f, a1 = 0.f, a2 = 0.f;
    #pragma unroll
    for (int k = 0; k < H1; ++k) {
        float hv = fmaxf(h[k], 0.f);
        a0 += hv * ws[k * H2 + col];
        a1 += hv * ws[512 + k * H2 + col];
        a2 += hv * ws[1024 + k * H2 + col];
    }
    Y[g]               = a0;
    Y[131072 + g]      = a1;
    Y[262144 + g]      = a2;
}

// ---------------- Kernel 4: T[h] += A @ Y[h] (atomic scatter, d=16, 3 heads) ----------------
__global__ __launch_bounds__(256) void k_spmm3(const int* __restrict__ rows,
                                               const int* __restrict__ cols,
                                               const float* __restrict__ vals,
                                               const float* __restrict__ Y,
                                               float* __restrict__ T, int E) {
    int t = blockIdx.x * 256 + threadIdx.x;
    int e = t / 12;                  // 12 threads / edge: 3 heads x 4-float chunks
    if (e >= E) return;
    int rem  = t - e * 12;
    int head = rem >> 2;
    int cg   = (rem & 3) * 4;
    int r = rows[e], c = cols[e];
    float v = vals[e];
    const float* y = Y + head * 131072;
    float4 x = *(const float4*)&y[c * H2 + cg];
    float* dst = T + head * 131072 + r * H2 + cg;
    atomicAdd(dst + 0, v * x.x);
    atomicAdd(dst + 1, v * x.y);
    atomicAdd(dst + 2, v * x.z);
    atomicAdd(dst + 3, v * x.w);
}

// ---------------- Kernel 5: per-row softmaxes + reparameterization -> z ----------------
__global__ __launch_bounds__(256) void k_final(const float* __restrict__ T,
                                               const float* __restrict__ s1,
                                               const float* __restrict__ s2,
                                               float* __restrict__ z) {
    int r = blockIdx.x * 256 + threadIdx.x;     // r < N
    if (r >= N_NODES) return;
    const float* tex = T + r * H2;
    const float* ten = T + 131072 + r * H2;
    const float* the = T + 262144 + r * H2;

    float en[H2], he[H2];
    float m1 = -1e30f, m2 = -1e30f;
    #pragma unroll
    for (int k = 0; k < H2; ++k) {
        en[k] = ten[k];
        he[k] = the[k];
        m1 = fmaxf(m1, en[k]);
        m2 = fmaxf(m2, he[k]);
    }
    float sum1 = 0.f, sum2 = 0.f;
    #pragma unroll
    for (int k = 0; k < H2; ++k) {
        en[k] = expf(en[k] - m1);  sum1 += en[k];
        he[k] = expf(he[k] - m2);  sum2 += he[k];
    }
    float inv1 = 1.f / sum1, inv2 = 1.f / sum2;
    #pragma unroll
    for (int k = 0; k < H2; ++k) {
        float z_en = expf(en[k] * inv1);               // exp(softmax)
        float z_he = 0.1f * expf(he[k] * inv2);        // 0.1*exp(softmax)
        float z_enn = z_en + s1[r * H2 + k] * z_he;
        z[r * H2 + k] = tex[k] + s2[r * H2 + k] * z_enn;
    }
}

// ---------------- Kernel 6: out = z @ z^T  (64x64 tiles, 4x4 per thread) ----------------
__global__ __launch_bounds__(256) void k_zzt(const float* __restrict__ z,
                                             float* __restrict__ out) {
    __shared__ float zi[64 * 17];    // padded rows: conflict-free scalar a-reads
    __shared__ float zjT[H2 * 64];   // transposed: conflict-free float4 b-reads
    int t  = threadIdx.x;
    int i0 = blockIdx.y * 64, j0 = blockIdx.x * 64;

    {   // stage: each thread moves one float4 for zi and one for zjT
        int c = t >> 2, q = (t & 3) * 4;
        float4 a = *(const float4*)&z[(i0 + c) * H2 + q];
        zi[c * 17 + q + 0] = a.x; zi[c * 17 + q + 1] = a.y;
        zi[c * 17 + q + 2] = a.z; zi[c * 17 + q + 3] = a.w;
        float4 b = *(const float4*)&z[(j0 + c) * H2 + q];
        zjT[(q + 0) * 64 + c] = b.x; zjT[(q + 1) * 64 + c] = b.y;
        zjT[(q + 2) * 64 + c] = b.z; zjT[(q + 3) * 64 + c] = b.w;
    }
    __syncthreads();

    int tx = t & 15, ty = t >> 4;
    float4 acc0 = {0,0,0,0}, acc1 = {0,0,0,0}, acc2 = {0,0,0,0}, acc3 = {0,0,0,0};
    const float4* zjT_v = (const float4*)zjT;
    #pragma unroll
    for (int k = 0; k < H2; ++k) {
        float4 b  = zjT_v[k * 16 + tx];
        float  a0 = zi[(ty * 4 + 0) * 17 + k];
        float  a1 = zi[(ty * 4 + 1) * 17 + k];
        float  a2 = zi[(ty * 4 + 2) * 17 + k];
        float  a3 = zi[(ty * 4 + 3) * 17 + k];
        FMA4(acc0, a0, b);
        FMA4(acc1, a1, b);
        FMA4(acc2, a2, b);
        FMA4(acc3, a3, b);
    }
    size_t base = (size_t)(i0 + ty * 4) * N_NODES + j0 + tx * 4;
    *(float4*)&out[base]               = acc0;
    *(float4*)&out[base + N_NODES]     = acc1;
    *(float4*)&out[base + 2 * N_NODES] = acc2;
    *(float4*)&out[base + 3 * N_NODES] = acc3;
}

// ---------------- Launch ----------------
extern "C" void kernel_launch(void* const* d_in, const int* in_sizes, int n_in,
                              void* d_out, int out_size, void* d_ws, size_t ws_size,
                              hipStream_t stream) {
    const float* feat = (const float*)d_in[0];
    const int*   rows = (const int*)d_in[1];
    const int*   cols = (const int*)d_in[2];
    const float* vals = (const float*)d_in[3];
    const float* W0   = (const float*)d_in[4];
    const float* W1   = (const float*)d_in[5];
    const float* W2   = (const float*)d_in[6];
    const float* W3   = (const float*)d_in[7];
    const float* s1   = (const float*)d_in[8];
    const float* s2   = (const float*)d_in[9];
    float* out = (float*)d_out;
    int E = in_sizes[1];

    float* ws    = (float*)d_ws;
    float* xw0   = ws;                // 262144 floats
    float* h1acc = ws + 262144;       // 262144 floats (atomic accum; zeroed)
    float* Y     = ws + 524288;       // 3 * 131072 floats
    float* T     = ws + 917504;       // 3 * 131072 floats (atomic accum; zeroed)
    float* z     = ws + 1310720;      // 131072 floats

    hipMemsetAsync(h1acc, 0, 262144 * sizeof(float), stream);
    hipMemsetAsync(T,     0, 393216 * sizeof(float), stream);

    k_xw0  <<<N_NODES / 32, 256, 0, stream>>>(feat, W0, xw0);
    k_spmm1<<<(E * 8 + 255) / 256, 256, 0, stream>>>(rows, cols, vals, xw0, h1acc, E);
    k_heads<<<(N_NODES * H2) / 256, 256, 0, stream>>>(h1acc, W1, W2, W3, Y);
    k_spmm3<<<(E * 12 + 255) / 256, 256, 0, stream>>>(rows, cols, vals, Y, T, E);
    k_final<<<N_NODES / 256, 256, 0, stream>>>(T, s1, s2, z);

    dim3 grid(N_NODES / 64, N_NODES / 64);
    k_zzt<<<grid, 256, 0, stream>>>(z, out);
}

// Round 2
// 359.156 us; speedup vs baseline: 1.2970x; 1.2970x over previous
//
#include <hip/hip_runtime.h>
#include <math.h>

#define N_NODES 8192
#define F_IN    512
#define H1      32
#define H2      16

#define FMA4(acc, s, v) do { (acc).x += (s)*(v).x; (acc).y += (s)*(v).y; \
                             (acc).z += (s)*(v).z; (acc).w += (s)*(v).w; } while(0)

// ---------------- Kernel 1: XW0 = features @ W0  [8192,512]x[512,32] ----------------
__global__ __launch_bounds__(256) void k_xw0(const float* __restrict__ feat,
                                             const float* __restrict__ W0,
                                             float* __restrict__ xw0) {
    __shared__ float w0s[F_IN * H1];            // 64 KiB
    float4* w0s_v = (float4*)w0s;
    const float4* W0_v = (const float4*)W0;
    int t = threadIdx.x;
    #pragma unroll
    for (int i = 0; i < 16; ++i) w0s_v[t + i * 256] = W0_v[t + i * 256];
    __syncthreads();

    int row = blockIdx.x * 32 + (t >> 3);       // 32 rows / block
    int cg  = (t & 7) * 4;                      // 4 cols / thread
    const float4* frow_v = (const float4*)(feat + (size_t)row * F_IN);

    float4 acc = {0.f, 0.f, 0.f, 0.f};
    #pragma unroll 4
    for (int k0 = 0; k0 < F_IN; k0 += 4) {
        float4 f  = frow_v[k0 >> 2];
        float4 w0 = *(float4*)&w0s[(k0 + 0) * H1 + cg];
        float4 w1 = *(float4*)&w0s[(k0 + 1) * H1 + cg];
        float4 w2 = *(float4*)&w0s[(k0 + 2) * H1 + cg];
        float4 w3 = *(float4*)&w0s[(k0 + 3) * H1 + cg];
        FMA4(acc, f.x, w0);
        FMA4(acc, f.y, w1);
        FMA4(acc, f.z, w2);
        FMA4(acc, f.w, w3);
    }
    *(float4*)&xw0[row * H1 + cg] = acc;
}

// ---------------- CSR build: histogram -> scan -> scatter ----------------
__global__ __launch_bounds__(256) void k_hist(const int* __restrict__ rows,
                                              int* __restrict__ cnt, int E) {
    int e = blockIdx.x * 256 + threadIdx.x;
    if (e < E) atomicAdd(&cnt[rows[e]], 1);
}

__global__ __launch_bounds__(256) void k_scan(const int* __restrict__ cnt,
                                              int* __restrict__ row_start,
                                              int* __restrict__ cursor) {
    __shared__ int part[256];
    int t = threadIdx.x;
    int base = t * 32;
    int local[32];
    int s = 0;
    #pragma unroll
    for (int i = 0; i < 32; ++i) { local[i] = cnt[base + i]; s += local[i]; }
    part[t] = s;
    __syncthreads();
    for (int off = 1; off < 256; off <<= 1) {
        int v = (t >= off) ? part[t - off] : 0;
        __syncthreads();
        part[t] += v;
        __syncthreads();
    }
    int run = (t == 0) ? 0 : part[t - 1];       // exclusive base for this chunk
    #pragma unroll
    for (int i = 0; i < 32; ++i) {
        row_start[base + i] = run;
        cursor[base + i]    = run;
        run += local[i];
    }
    if (t == 255) row_start[N_NODES] = run;
}

__global__ __launch_bounds__(256) void k_scatter(const int* __restrict__ rows,
                                                 const int* __restrict__ cols,
                                                 const float* __restrict__ vals,
                                                 int* __restrict__ cursor,
                                                 int2* __restrict__ edges, int E) {
    int e = blockIdx.x * 256 + threadIdx.x;
    if (e >= E) return;
    int pos = atomicAdd(&cursor[rows[e]], 1);
    edges[pos] = make_int2(cols[e], __float_as_int(vals[e]));
}

// ---------------- Kernel 2: h1 = relu(A @ XW0) via CSR gather (16 thr/row) ----------------
__global__ __launch_bounds__(256) void k_spmm1(const int* __restrict__ row_start,
                                               const int2* __restrict__ edges,
                                               const float* __restrict__ xw0,
                                               float* __restrict__ h1) {
    int t  = blockIdx.x * 256 + threadIdx.x;
    int r  = t >> 4;
    int tt = t & 15;
    int part = (tt & 7) * 4;                    // which float4 of the 32-wide row
    int half = tt >> 3;                         // edge-split factor 2
    int s = row_start[r], e = row_start[r + 1];
    float4 acc = {0.f, 0.f, 0.f, 0.f};
    for (int i = s + half; i < e; i += 2) {
        int2 ed = edges[i];
        float v = __int_as_float(ed.y);
        float4 x = *(const float4*)&xw0[ed.x * H1 + part];
        FMA4(acc, v, x);
    }
    acc.x += __shfl_xor(acc.x, 8);
    acc.y += __shfl_xor(acc.y, 8);
    acc.z += __shfl_xor(acc.z, 8);
    acc.w += __shfl_xor(acc.w, 8);
    if (half == 0) {
        acc.x = fmaxf(acc.x, 0.f); acc.y = fmaxf(acc.y, 0.f);
        acc.z = fmaxf(acc.z, 0.f); acc.w = fmaxf(acc.w, 0.f);
        *(float4*)&h1[r * H1 + part] = acc;
    }
}

// ---------------- Kernel 3: Y[N][48] = h1 @ {W1,W2,W3} ----------------
__global__ __launch_bounds__(256) void k_heads(const float* __restrict__ h1,
                                               const float* __restrict__ W1,
                                               const float* __restrict__ W2,
                                               const float* __restrict__ W3,
                                               float* __restrict__ Y) {
    __shared__ float ws[3 * H1 * H2];           // 6 KiB
    int t = threadIdx.x;
    for (int i = t; i < H1 * H2; i += 256) {
        ws[i]        = W1[i];
        ws[512 + i]  = W2[i];
        ws[1024 + i] = W3[i];
    }
    __syncthreads();

    int g   = blockIdx.x * 256 + t;             // g < N*H2
    int row = g >> 4, col = g & 15;
    const float* h = &h1[row * H1];
    float a0 = 0.f, a1 = 0.f, a2 = 0.f;
    #pragma unroll
    for (int k = 0; k < H1; ++k) {
        float hv = h[k];                        // already relu'd
        a0 += hv * ws[k * H2 + col];
        a1 += hv * ws[512 + k * H2 + col];
        a2 += hv * ws[1024 + k * H2 + col];
    }
    float* yr = &Y[row * 48];
    yr[col]      = a0;
    yr[16 + col] = a1;
    yr[32 + col] = a2;
}

// ---------------- Kernel 4: T[N][48] = A @ Y via CSR gather (16 thr/row) ----------------
__global__ __launch_bounds__(256) void k_spmm3(const int* __restrict__ row_start,
                                               const int2* __restrict__ edges,
                                               const float* __restrict__ Y,
                                               float* __restrict__ T) {
    int t  = blockIdx.x * 256 + threadIdx.x;
    int r  = t >> 4;
    int tt = t & 15;
    int cg = (tt & 3) * 4;                      // which float4 of each head's 16
    int q  = tt >> 2;                           // edge-split factor 4
    int s = row_start[r], e = row_start[r + 1];
    float4 a0 = {0,0,0,0}, a1 = {0,0,0,0}, a2 = {0,0,0,0};
    for (int i = s + q; i < e; i += 4) {
        int2 ed = edges[i];
        float v = __int_as_float(ed.y);
        const float* y = &Y[ed.x * 48];
        float4 y0 = *(const float4*)&y[cg];
        float4 y1 = *(const float4*)&y[16 + cg];
        float4 y2 = *(const float4*)&y[32 + cg];
        FMA4(a0, v, y0);
        FMA4(a1, v, y1);
        FMA4(a2, v, y2);
    }
#define RED4(a) do { \
        (a).x += __shfl_xor((a).x, 4); (a).y += __shfl_xor((a).y, 4); \
        (a).z += __shfl_xor((a).z, 4); (a).w += __shfl_xor((a).w, 4); \
        (a).x += __shfl_xor((a).x, 8); (a).y += __shfl_xor((a).y, 8); \
        (a).z += __shfl_xor((a).z, 8); (a).w += __shfl_xor((a).w, 8); } while(0)
    RED4(a0); RED4(a1); RED4(a2);
    if (q == 0) {
        float* tr = &T[r * 48];
        *(float4*)&tr[cg]      = a0;
        *(float4*)&tr[16 + cg] = a1;
        *(float4*)&tr[32 + cg] = a2;
    }
}

// ---------------- Kernel 5: per-row softmaxes + reparameterization -> z ----------------
__global__ __launch_bounds__(256) void k_final(const float* __restrict__ T,
                                               const float* __restrict__ s1,
                                               const float* __restrict__ s2,
                                               float* __restrict__ z) {
    int r = blockIdx.x * 256 + threadIdx.x;     // r < N
    if (r >= N_NODES) return;
    const float* tex = T + r * 48;
    const float* ten = tex + 16;
    const float* the = tex + 32;

    float en[H2], he[H2];
    float m1 = -1e30f, m2 = -1e30f;
    #pragma unroll
    for (int k = 0; k < H2; ++k) {
        en[k] = ten[k];
        he[k] = the[k];
        m1 = fmaxf(m1, en[k]);
        m2 = fmaxf(m2, he[k]);
    }
    float sum1 = 0.f, sum2 = 0.f;
    #pragma unroll
    for (int k = 0; k < H2; ++k) {
        en[k] = expf(en[k] - m1);  sum1 += en[k];
        he[k] = expf(he[k] - m2);  sum2 += he[k];
    }
    float inv1 = 1.f / sum1, inv2 = 1.f / sum2;
    #pragma unroll
    for (int k = 0; k < H2; ++k) {
        float z_en = expf(en[k] * inv1);               // exp(softmax)
        float z_he = 0.1f * expf(he[k] * inv2);        // 0.1*exp(softmax)
        float z_enn = z_en + s1[r * H2 + k] * z_he;
        z[r * H2 + k] = tex[k] + s2[r * H2 + k] * z_enn;
    }
}

// ---------------- Kernel 6: out = z @ z^T  (64x64 tiles, 4x4 per thread) ----------------
__global__ __launch_bounds__(256) void k_zzt(const float* __restrict__ z,
                                             float* __restrict__ out) {
    __shared__ float zi[64 * 17];    // padded rows: conflict-free scalar a-reads
    __shared__ float zjT[H2 * 64];   // transposed: conflict-free float4 b-reads
    int t  = threadIdx.x;
    int i0 = blockIdx.y * 64, j0 = blockIdx.x * 64;

    {   // stage: each thread moves one float4 for zi and one for zjT
        int c = t >> 2, q = (t & 3) * 4;
        float4 a = *(const float4*)&z[(i0 + c) * H2 + q];
        zi[c * 17 + q + 0] = a.x; zi[c * 17 + q + 1] = a.y;
        zi[c * 17 + q + 2] = a.z; zi[c * 17 + q + 3] = a.w;
        float4 b = *(const float4*)&z[(j0 + c) * H2 + q];
        zjT[(q + 0) * 64 + c] = b.x; zjT[(q + 1) * 64 + c] = b.y;
        zjT[(q + 2) * 64 + c] = b.z; zjT[(q + 3) * 64 + c] = b.w;
    }
    __syncthreads();

    int tx = t & 15, ty = t >> 4;
    float4 acc0 = {0,0,0,0}, acc1 = {0,0,0,0}, acc2 = {0,0,0,0}, acc3 = {0,0,0,0};
    const float4* zjT_v = (const float4*)zjT;
    #pragma unroll
    for (int k = 0; k < H2; ++k) {
        float4 b  = zjT_v[k * 16 + tx];
        float  a0 = zi[(ty * 4 + 0) * 17 + k];
        float  a1 = zi[(ty * 4 + 1) * 17 + k];
        float  a2 = zi[(ty * 4 + 2) * 17 + k];
        float  a3 = zi[(ty * 4 + 3) * 17 + k];
        FMA4(acc0, a0, b);
        FMA4(acc1, a1, b);
        FMA4(acc2, a2, b);
        FMA4(acc3, a3, b);
    }
    size_t base = (size_t)(i0 + ty * 4) * N_NODES + j0 + tx * 4;
    *(float4*)&out[base]               = acc0;
    *(float4*)&out[base + N_NODES]     = acc1;
    *(float4*)&out[base + 2 * N_NODES] = acc2;
    *(float4*)&out[base + 3 * N_NODES] = acc3;
}

// ---------------- Launch ----------------
extern "C" void kernel_launch(void* const* d_in, const int* in_sizes, int n_in,
                              void* d_out, int out_size, void* d_ws, size_t ws_size,
                              hipStream_t stream) {
    const float* feat = (const float*)d_in[0];
    const int*   rows = (const int*)d_in[1];
    const int*   cols = (const int*)d_in[2];
    const float* vals = (const float*)d_in[3];
    const float* W0   = (const float*)d_in[4];
    const float* W1   = (const float*)d_in[5];
    const float* W2   = (const float*)d_in[6];
    const float* W3   = (const float*)d_in[7];
    const float* s1   = (const float*)d_in[8];
    const float* s2   = (const float*)d_in[9];
    float* out = (float*)d_out;
    int E = in_sizes[1];

    float* ws        = (float*)d_ws;
    float* xw0       = ws;                     // 262144 floats
    float* h1        = ws + 262144;            // 262144 floats
    float* Y         = ws + 524288;            // N*48 = 393216 floats
    float* T         = ws + 917504;            // 393216 floats
    float* z         = ws + 1310720;           // 131072 floats
    int*   cnt       = (int*)(ws + 1441792);   // 8192 ints
    int*   row_start = (int*)(ws + 1449984);   // 8193 ints
    int*   cursor    = (int*)(ws + 1458432);   // 8192 ints
    int2*  edges     = (int2*)(ws + 1466624);  // E int2 (8B-aligned)

    hipMemsetAsync(cnt, 0, N_NODES * sizeof(int), stream);

    k_hist   <<<(E + 255) / 256, 256, 0, stream>>>(rows, cnt, E);
    k_scan   <<<1, 256, 0, stream>>>(cnt, row_start, cursor);
    k_scatter<<<(E + 255) / 256, 256, 0, stream>>>(rows, cols, vals, cursor, edges, E);

    k_xw0  <<<N_NODES / 32, 256, 0, stream>>>(feat, W0, xw0);
    k_spmm1<<<N_NODES * 16 / 256, 256, 0, stream>>>(row_start, edges, xw0, h1);
    k_heads<<<N_NODES * H2 / 256, 256, 0, stream>>>(h1, W1, W2, W3, Y);
    k_spmm3<<<N_NODES * 16 / 256, 256, 0, stream>>>(row_start, edges, Y, T);
    k_final<<<N_NODES / 256, 256, 0, stream>>>(T, s1, s2, z);

    dim3 grid(N_NODES / 64, N_NODES / 64);
    k_zzt<<<grid, 256, 0, stream>>>(z, out);
}